// Round 2
// baseline (151.809 us; speedup 1.0000x reference)
//
#include <hip/hip_runtime.h>
#include <stdint.h>

// GraphCut fused contrastive loss, MI355X (gfx950) — round 2.
// loss = -mean_i( sum_{j!=i} sign_ij * exp(sim_ij - rowmax_i) ), sim = (F F^T)/0.2.
// Round-1 lesson: column-major B-fragment loads were uncoalesced (32 TA
// transactions per load). Fix: prep stores features in MFMA-fragment order so
// fragment loads are coalesced 1-KB wave loads. No LDS needed. Each wave owns
// 2 A-tiles (64 rows) to halve fragment traffic per MFMA.

#define M_ROWS 8192
#define K_DIM  128
#define NCHUNK 16
#define CHUNK_COLS (M_ROWS / NCHUNK)      // 512
#define NT_PER_CHUNK (CHUNK_COLS / 32)    // 16
#define INV_T_LOG2E 7.213475204444817f    // (1/0.2) * log2(e)

typedef __bf16 bf16x8 __attribute__((ext_vector_type(8)));
typedef float  f32x16 __attribute__((ext_vector_type(16)));
typedef unsigned short ushort8v __attribute__((ext_vector_type(8)));

// FB fragment layout: 16-B granule index = (ct*16 + s8*2 + l5)*32 + lm,
// holding bf16 F[ct*32 + lm][16*s8 + 8*l5 + e], e = 0..7. A wave's fragment
// load (lane = l5*32+lm) is then 64 consecutive granules = 1 KB contiguous.

// ---- prep: fp32 -> bf16 (RNE) into fragment layout + per-row self-dot ----
__global__ __launch_bounds__(256) void prep_kernel(const float* __restrict__ f,
                                                   ushort8v* __restrict__ FB,
                                                   float* __restrict__ selfdot,
                                                   float* __restrict__ out) {
    const int t    = threadIdx.x;
    const int row  = blockIdx.x * 16 + (t >> 4);
    const int slot = t & 15;                      // = s8*2 + l5
    const float4 v0 = *(const float4*)(f + (size_t)row * K_DIM + slot * 8);
    const float4 v1 = *(const float4*)(f + (size_t)row * K_DIM + slot * 8 + 4);
    float x[8] = {v0.x, v0.y, v0.z, v0.w, v1.x, v1.y, v1.z, v1.w};
    ushort8v h;
    float ss = 0.f;
#pragma unroll
    for (int e = 0; e < 8; ++e) {
        uint32_t u = __builtin_bit_cast(uint32_t, x[e]);
        uint32_t r = (u + 0x7FFFu + ((u >> 16) & 1u)) >> 16;   // RNE to bf16
        h[e] = (unsigned short)r;
        float b = __builtin_bit_cast(float, r << 16);
        ss += b * b;
    }
#pragma unroll
    for (int off = 1; off < 16; off <<= 1) ss += __shfl_xor(ss, off, 64);
    if (slot == 0) selfdot[row] = ss;
    const int ct = row >> 5, lm = row & 31;
    FB[(size_t)(ct * 16 + slot) * 32 + lm] = h;
    if (blockIdx.x == 0 && t == 0) out[0] = 0.f;   // d_out is poisoned 0xAA
}

// ---- main fused kernel: 512 blocks = 32 row-groups x 16 col-chunks ----
// Block = 4 waves; wave owns 64 rows (2 A-tiles), sweeps 512 cols in 16 tiles.
__global__ __launch_bounds__(256, 2) void fused_kernel(const ushort8v* __restrict__ FB,
                                                       const int* __restrict__ labels,
                                                       const float* __restrict__ selfdot,
                                                       float* __restrict__ partials) {
    const int blk  = blockIdx.x;
    const int rg   = blk >> 4;          // row group (256 rows)
    const int ch   = blk & 15;          // col chunk (512 cols); blk&7 = XCD -> 256 KB B set
    const int w    = threadIdx.x >> 6;
    const int lane = threadIdx.x & 63;
    const int lm   = lane & 31;
    const int l5   = lane >> 5;
    const int row0 = rg * 256 + w * 64;
    const int ct0  = row0 >> 5;

    // resident A fragments, 2 tiles x 8 k-slices (coalesced loads)
    bf16x8 af[2][8];
#pragma unroll
    for (int tt = 0; tt < 2; ++tt)
#pragma unroll
        for (int s8 = 0; s8 < 8; ++s8)
            af[tt][s8] = (const bf16x8&)FB[(size_t)((ct0 + tt) * 16 + s8 * 2 + l5) * 32 + lm];

    // online-softmax state per owned C-row (C/D layout: row = (r&3)+8*(r>>2)+4*l5)
    float m[2][16], s[2][16];
    float minm = 1e30f;
#pragma unroll
    for (int tt = 0; tt < 2; ++tt)
#pragma unroll
        for (int r = 0; r < 16; ++r) {
            const int grow = row0 + tt * 32 + (r & 3) + 8 * (r >> 2) + 4 * l5;
            m[tt][r] = selfdot[grow];   // diag dot ~= row max; exact via online updates
            s[tt][r] = 0.f;
            minm = fminf(minm, m[tt][r]);
        }

    const int ctb0 = ch * NT_PER_CHUNK;
    bf16x8 bf[8];
#pragma unroll
    for (int s8 = 0; s8 < 8; ++s8)
        bf[s8] = (const bf16x8&)FB[(size_t)(ctb0 * 16 + s8 * 2 + l5) * 32 + lm];

#pragma unroll 2
    for (int nt = 0; nt < NT_PER_CHUNK; ++nt) {
        const int jcol = (ctb0 + nt) * 32 + lm;
        f32x16 a0 = {}, a1 = {};
#pragma unroll
        for (int s8 = 0; s8 < 8; ++s8) {
            a0 = __builtin_amdgcn_mfma_f32_32x32x16_bf16(af[0][s8], bf[s8], a0, 0, 0, 0);
            a1 = __builtin_amdgcn_mfma_f32_32x32x16_bf16(af[1][s8], bf[s8], a1, 0, 0, 0);
        }
        // branchless prefetch of the next col tile (same BB as the MFMA chain)
        const int ctn = ctb0 + (nt < NT_PER_CHUNK - 1 ? nt + 1 : nt);
        bf16x8 tmp[8];
#pragma unroll
        for (int s8 = 0; s8 < 8; ++s8)
            tmp[s8] = (const bf16x8&)FB[(size_t)(ctn * 16 + s8 * 2 + l5) * 32 + lm];
        float amax = a0[0];
#pragma unroll
        for (int r = 1; r < 16; ++r) amax = fmaxf(amax, a0[r]);
#pragma unroll
        for (int r = 0; r < 16; ++r) amax = fmaxf(amax, a1[r]);
#pragma unroll
        for (int s8 = 0; s8 < 8; ++s8) bf[s8] = tmp[s8];
        // wave-uniform skip: exp((acc-m)/T) == 0 in fp32 when acc - m < -21
        if (__any(amax > minm - 22.f)) {
            const int labj = labels[jcol];
#pragma unroll
            for (int tt = 0; tt < 2; ++tt)
#pragma unroll
                for (int r = 0; r < 16; ++r) {
                    const int grow = row0 + tt * 32 + (r & 3) + 8 * (r >> 2) + 4 * l5;
                    const float acc = tt ? a1[r] : a0[r];
                    float d    = acc - m[tt][r];
                    float sign = (labj == labels[grow]) ? 1.f : -1.f;
                    if (jcol == grow) sign = 0.f;          // mask diagonal
                    bool  p = d > 0.f;
                    float e = exp2f(fminf(d, -d) * INV_T_LOG2E);
                    float xx = p ? s[tt][r] : sign;
                    float yy = p ? sign : s[tt][r];
                    s[tt][r] = fmaf(xx, e, yy);            // online rescale-or-add
                    m[tt][r] = fmaxf(m[tt][r], acc);
                }
            minm = m[0][0];
#pragma unroll
            for (int tt = 0; tt < 2; ++tt)
#pragma unroll
                for (int r = 0; r < 16; ++r) minm = fminf(minm, m[tt][r]);
        }
    }

    // merge the 32 column-lane partials of each row
#pragma unroll
    for (int off = 1; off < 32; off <<= 1) {
#pragma unroll
        for (int tt = 0; tt < 2; ++tt)
#pragma unroll
            for (int r = 0; r < 16; ++r) {
                float mo = __shfl_xor(m[tt][r], off, 64);
                float so = __shfl_xor(s[tt][r], off, 64);
                float d  = mo - m[tt][r];
                bool  p  = d > 0.f;
                float e  = exp2f(fminf(d, -d) * INV_T_LOG2E);
                s[tt][r] = p ? fmaf(s[tt][r], e, so) : fmaf(so, e, s[tt][r]);
                m[tt][r] = fmaxf(m[tt][r], mo);
            }
    }
    if (lm == 0) {
#pragma unroll
        for (int tt = 0; tt < 2; ++tt)
#pragma unroll
            for (int r = 0; r < 16; ++r) {
                const int grow = row0 + tt * 32 + (r & 3) + 8 * (r >> 2) + 4 * l5;
                float* p = partials + ((size_t)grow * NCHUNK + ch) * 2;
                p[0] = m[tt][r];
                p[1] = s[tt][r];
            }
    }
}

// ---- merge 16 chunk-partials per row, reduce, atomic add ----
__global__ __launch_bounds__(256) void merge_kernel(const float* __restrict__ partials,
                                                    float* __restrict__ out) {
    const int g = blockIdx.x * 256 + threadIdx.x;    // row id
    float M = -1e30f, S = 0.f;
#pragma unroll
    for (int c = 0; c < NCHUNK; ++c) {
        const float* p = partials + ((size_t)g * NCHUNK + c) * 2;
        float mo = p[0], so = p[1];
        float d  = mo - M;
        bool  pr = d > 0.f;
        float e  = exp2f(fminf(d, -d) * INV_T_LOG2E);
        S = pr ? fmaf(S, e, so) : fmaf(so, e, S);
        M = fmaxf(M, mo);
    }
    float val = -S * (1.0f / 8192.0f);
#pragma unroll
    for (int off = 1; off < 64; off <<= 1) val += __shfl_xor(val, off, 64);
    __shared__ float red[4];
    if ((threadIdx.x & 63) == 0) red[threadIdx.x >> 6] = val;
    __syncthreads();
    if (threadIdx.x == 0) atomicAdd(out, red[0] + red[1] + red[2] + red[3]);
}

extern "C" void kernel_launch(void* const* d_in, const int* in_sizes, int n_in,
                              void* d_out, int out_size, void* d_ws, size_t ws_size,
                              hipStream_t stream) {
    const float* feat   = (const float*)d_in[0];
    const int*   labels = (const int*)d_in[1];
    float*       out    = (float*)d_out;
    char*        ws     = (char*)d_ws;

    ushort8v* FB       = (ushort8v*)ws;                                        // 2 MB
    float*    selfdot  = (float*)(ws + (size_t)M_ROWS * K_DIM * 2);            // 32 KB
    float*    partials = (float*)(ws + (size_t)M_ROWS * K_DIM * 2 + M_ROWS * 4); // 1 MB

    prep_kernel<<<M_ROWS / 16, 256, 0, stream>>>(feat, FB, selfdot, out);
    fused_kernel<<<(M_ROWS / 256) * NCHUNK, 256, 0, stream>>>(FB, labels, selfdot, partials);
    merge_kernel<<<M_ROWS / 256, 256, 0, stream>>>(partials, out);
}

// Round 3
// 105.052 us; speedup vs baseline: 1.4451x; 1.4451x over previous
//
#include <hip/hip_runtime.h>
#include <stdint.h>

// GraphCut fused contrastive loss, MI355X (gfx950) — round 3.
// loss = -mean_i( sum_{j!=i} sign_ij * exp(sim_ij - rowmax_i) ), sim = (F F^T)/0.2.
// R1 lesson: transposed B loads were uncoalesced -> latency-bound (81 us).
// R2 lesson: 2 A-tiles + prefetch + __launch_bounds__(256,2) -> 85 MB of VGPR
//            spill traffic (97 us). Fix: keep the fragment-ordered layout
//            (coalesced loads), revert to 1 A-tile/wave, no forced occupancy.
// Block = 4 waves sharing one column chunk: all waves sweep the SAME B-tile
// sequence (L1-shared), each wave owns a different 32-row A-tile.

#define M_ROWS 8192
#define K_DIM  128
#define NCHUNK 16
#define CHUNK_COLS (M_ROWS / NCHUNK)      // 512
#define NT_PER_CHUNK (CHUNK_COLS / 32)    // 16
#define INV_T_LOG2E 7.213475204444817f    // (1/0.2) * log2(e)

typedef __bf16 bf16x8 __attribute__((ext_vector_type(8)));
typedef float  f32x16 __attribute__((ext_vector_type(16)));
typedef unsigned short ushort8v __attribute__((ext_vector_type(8)));

// FB fragment layout: 16-B granule index = (ct*16 + s8*2 + l5)*32 + lm,
// holding bf16 F[ct*32 + lm][16*s8 + 8*l5 + e], e = 0..7. A wave's fragment
// load (lane = l5*32+lm) is 64 consecutive granules = 1 KB contiguous.

// ---- prep: fp32 -> bf16 (RNE) into fragment layout + per-row self-dot ----
__global__ __launch_bounds__(256) void prep_kernel(const float* __restrict__ f,
                                                   ushort8v* __restrict__ FB,
                                                   float* __restrict__ selfdot,
                                                   float* __restrict__ out) {
    const int t    = threadIdx.x;
    const int row  = blockIdx.x * 16 + (t >> 4);
    const int slot = t & 15;                      // = s8*2 + l5
    const float4 v0 = *(const float4*)(f + (size_t)row * K_DIM + slot * 8);
    const float4 v1 = *(const float4*)(f + (size_t)row * K_DIM + slot * 8 + 4);
    float x[8] = {v0.x, v0.y, v0.z, v0.w, v1.x, v1.y, v1.z, v1.w};
    ushort8v h;
    float ss = 0.f;
#pragma unroll
    for (int e = 0; e < 8; ++e) {
        uint32_t u = __builtin_bit_cast(uint32_t, x[e]);
        uint32_t r = (u + 0x7FFFu + ((u >> 16) & 1u)) >> 16;   // RNE to bf16
        h[e] = (unsigned short)r;
        float b = __builtin_bit_cast(float, r << 16);
        ss += b * b;
    }
#pragma unroll
    for (int off = 1; off < 16; off <<= 1) ss += __shfl_xor(ss, off, 64);
    if (slot == 0) selfdot[row] = ss;
    const int ct = row >> 5, lm = row & 31;
    FB[(size_t)(ct * 16 + slot) * 32 + lm] = h;
    if (blockIdx.x == 0 && t == 0) out[0] = 0.f;   // d_out is poisoned 0xAA
}

// ---- main fused kernel: 1024 blocks = 64 row-groups(128 rows) x 16 chunks ----
__global__ __launch_bounds__(256) void fused_kernel(const ushort8v* __restrict__ FB,
                                                    const int* __restrict__ labels,
                                                    const float* __restrict__ selfdot,
                                                    float* __restrict__ partials) {
    const int blk  = blockIdx.x;
    const int rg   = blk >> 4;          // row group (128 rows)
    const int ch   = blk & 15;          // col chunk (512 cols)
    const int w    = threadIdx.x >> 6;
    const int lane = threadIdx.x & 63;
    const int lm   = lane & 31;
    const int l5   = lane >> 5;
    const int row0 = rg * 128 + w * 32;
    const int ct0  = row0 >> 5;

    // resident A fragments (coalesced 1-KB wave loads)
    bf16x8 af[8];
#pragma unroll
    for (int s8 = 0; s8 < 8; ++s8)
        af[s8] = (const bf16x8&)FB[(size_t)(ct0 * 16 + s8 * 2 + l5) * 32 + lm];

    // online-softmax state per owned C-row (C/D layout: row = (r&3)+8*(r>>2)+4*l5)
    float m[16], s[16];
    float minm = 1e30f;
#pragma unroll
    for (int r = 0; r < 16; ++r) {
        m[r] = selfdot[row0 + (r & 3) + 8 * (r >> 2) + 4 * l5];  // diag dot ~ row max
        s[r] = 0.f;
        minm = fminf(minm, m[r]);
    }

    const int ctb0 = ch * NT_PER_CHUNK;
    for (int nt = 0; nt < NT_PER_CHUNK; ++nt) {
        const int jcol = (ctb0 + nt) * 32 + lm;
        bf16x8 bf[8];
#pragma unroll
        for (int s8 = 0; s8 < 8; ++s8)
            bf[s8] = (const bf16x8&)FB[(size_t)((ctb0 + nt) * 16 + s8 * 2 + l5) * 32 + lm];
        f32x16 acc = {};
#pragma unroll
        for (int s8 = 0; s8 < 8; ++s8)
            acc = __builtin_amdgcn_mfma_f32_32x32x16_bf16(af[s8], bf[s8], acc, 0, 0, 0);

        float amax = acc[0];
#pragma unroll
        for (int r = 1; r < 16; ++r) amax = fmaxf(amax, acc[r]);
        // wave-uniform skip: exp((acc-m)/T) == 0 in fp32 when acc - m < -21
        if (__any(amax > minm - 22.f)) {
            const int labj = labels[jcol];
#pragma unroll
            for (int r = 0; r < 16; ++r) {
                const int grow = row0 + (r & 3) + 8 * (r >> 2) + 4 * l5;
                float d    = acc[r] - m[r];
                float sign = (labj == labels[grow]) ? 1.f : -1.f;
                if (jcol == grow) sign = 0.f;              // mask diagonal
                bool  p = d > 0.f;
                float e = exp2f(fminf(d, -d) * INV_T_LOG2E);
                float xx = p ? s[r] : sign;
                float yy = p ? sign : s[r];
                s[r] = fmaf(xx, e, yy);                    // online rescale-or-add
                m[r] = fmaxf(m[r], acc[r]);
            }
            minm = m[0];
#pragma unroll
            for (int r = 1; r < 16; ++r) minm = fminf(minm, m[r]);
        }
    }

    // merge the 32 column-lane partials of each row (offs stay within l5 half)
#pragma unroll
    for (int off = 1; off < 32; off <<= 1) {
#pragma unroll
        for (int r = 0; r < 16; ++r) {
            float mo = __shfl_xor(m[r], off, 64);
            float so = __shfl_xor(s[r], off, 64);
            float d  = mo - m[r];
            bool  p  = d > 0.f;
            float e  = exp2f(fminf(d, -d) * INV_T_LOG2E);
            s[r] = p ? fmaf(s[r], e, so) : fmaf(so, e, s[r]);
            m[r] = fmaxf(m[r], mo);
        }
    }
    if (lm == 0) {
#pragma unroll
        for (int r = 0; r < 16; ++r) {
            const int grow = row0 + (r & 3) + 8 * (r >> 2) + 4 * l5;
            float* p = partials + ((size_t)grow * NCHUNK + ch) * 2;
            p[0] = m[r];
            p[1] = s[r];
        }
    }
}

// ---- merge 16 chunk-partials per row, reduce, atomic add ----
__global__ __launch_bounds__(256) void merge_kernel(const float* __restrict__ partials,
                                                    float* __restrict__ out) {
    const int g = blockIdx.x * 256 + threadIdx.x;    // row id
    float M = -1e30f, S = 0.f;
#pragma unroll
    for (int c = 0; c < NCHUNK; ++c) {
        const float* p = partials + ((size_t)g * NCHUNK + c) * 2;
        float mo = p[0], so = p[1];
        float d  = mo - M;
        bool  pr = d > 0.f;
        float e  = exp2f(fminf(d, -d) * INV_T_LOG2E);
        S = pr ? fmaf(S, e, so) : fmaf(so, e, S);
        M = fmaxf(M, mo);
    }
    float val = -S * (1.0f / 8192.0f);
#pragma unroll
    for (int off = 1; off < 64; off <<= 1) val += __shfl_xor(val, off, 64);
    __shared__ float red[4];
    if ((threadIdx.x & 63) == 0) red[threadIdx.x >> 6] = val;
    __syncthreads();
    if (threadIdx.x == 0) atomicAdd(out, red[0] + red[1] + red[2] + red[3]);
}

extern "C" void kernel_launch(void* const* d_in, const int* in_sizes, int n_in,
                              void* d_out, int out_size, void* d_ws, size_t ws_size,
                              hipStream_t stream) {
    const float* feat   = (const float*)d_in[0];
    const int*   labels = (const int*)d_in[1];
    float*       out    = (float*)d_out;
    char*        ws     = (char*)d_ws;

    ushort8v* FB       = (ushort8v*)ws;                                          // 2 MB
    float*    selfdot  = (float*)(ws + (size_t)M_ROWS * K_DIM * 2);              // 32 KB
    float*    partials = (float*)(ws + (size_t)M_ROWS * K_DIM * 2 + M_ROWS * 4); // 1 MB

    prep_kernel<<<M_ROWS / 16, 256, 0, stream>>>(feat, FB, selfdot, out);
    fused_kernel<<<(M_ROWS / 128) * NCHUNK, 256, 0, stream>>>(FB, labels, selfdot, partials);
    merge_kernel<<<M_ROWS / 256, 256, 0, stream>>>(partials, out);
}